// Round 11
// baseline (604.952 us; speedup 1.0000x reference)
//
#include <hip/hip_runtime.h>
#include <hip/hip_bf16.h>
#include <cstdint>
#include <cstddef>

typedef unsigned short u16;
typedef __attribute__((ext_vector_type(8))) short bf16x8;
typedef __attribute__((ext_vector_type(4))) float f32x4;

#define MFMA16(a,b,c) __builtin_amdgcn_mfma_f32_16x16x32_bf16(a,b,c,0,0,0)
#define GLL16(gp, lp) __builtin_amdgcn_global_load_lds( \
    (const __attribute__((address_space(1))) void*)(gp), \
    (__attribute__((address_space(3))) void*)(lp), 16, 0, 0)

static constexpr int kB = 8, kH = 12, kN = 1025, kC = 768, kD = 64;
static constexpr int kBH = kB*kH;          // 96
static constexpr int kNP = 1056;           // padded N (33*32)
static constexpr int kM  = kB*kN;          // 8200
static constexpr float kScale = 0.125f;

__device__ __forceinline__ u16 f2b(float f){
  unsigned u = __builtin_bit_cast(unsigned, f);
  u = (u + 0x7fffu + ((u>>16)&1u)) >> 16;
  return (u16)u;
}
__device__ __forceinline__ float b2f(u16 s){
  unsigned u = ((unsigned)s)<<16;
  return __builtin_bit_cast(float, u);
}
// pack two f32 -> one dword of 2 bf16 (lo=a, hi=b), HW RNE (T12 recipe)
__device__ __forceinline__ unsigned pkbf(float a, float b){
  unsigned r;
  asm("v_cvt_pk_bf16_f32 %0, %1, %2" : "=v"(r) : "v"(a), "v"(b));
  return r;
}
// bijective XCD-chunked swizzle (m204): contiguous work chunk per XCD
__device__ __forceinline__ int xcd_swz(int orig, int nwg){
  int q = nwg>>3, r = nwg&7;
  int xcd = orig&7, idx = orig>>3;
  return (xcd<r ? xcd*(q+1) : r*(q+1)+(xcd-r)*q) + idx;
}

// ---------------- fused prep: x->bf16, weights->bf16, mask normalize --------
// blocks [0,6150): conv_x ; [6150,8454): conv_w ; [8454,8486): mask
__global__ __launch_bounds__(256) void k_prep(const float4* __restrict__ x,
    const float* __restrict__ w0, const float* __restrict__ w1,
    const float* __restrict__ w2, const float* __restrict__ w3,
    const unsigned char* __restrict__ m,
    u16* __restrict__ xb, u16* __restrict__ wb, int* __restrict__ maskn){
  __shared__ int cnt;
  const int bid = blockIdx.x;
  if (bid < 6150){
    int i = bid*256 + threadIdx.x;          // exactly 1,574,400
    float4 v = x[i];
    ushort4 o; o.x=f2b(v.x); o.y=f2b(v.y); o.z=f2b(v.z); o.w=f2b(v.w);
    *reinterpret_cast<ushort4*>(xb + (size_t)i*4) = o;
  } else if (bid < 8454){
    int j = (bid-6150)*256 + threadIdx.x;   // exactly 589,824
    int sel = j/147456, i = j - sel*147456;
    const float* ws[4] = {w0,w1,w2,w3};
    float4 v = reinterpret_cast<const float4*>(ws[sel])[i];
    ushort4 o; o.x=f2b(v.x); o.y=f2b(v.y); o.z=f2b(v.z); o.w=f2b(v.w);
    *reinterpret_cast<ushort4*>(wb + (size_t)sel*589824 + (size_t)i*4) = o;
  } else {
    // mask dtype detect (bool8 vs int32/f32) on first 1024 bytes, then slice
    if (threadIdx.x==0) cnt = 0;
    __syncthreads();
    int local = 0;
    for (int i=threadIdx.x; i<1024; i+=256) local += (m[i]!=0);
    atomicAdd(&cnt, local);
    __syncthreads();
    bool b8 = (cnt > 512);
    int lb = bid - 8454;                    // 0..31
    for (int i = lb*256 + threadIdx.x; i < kM; i += 32*256){
      int v = b8 ? (m[i]!=0) : (reinterpret_cast<const int*>(m)[i] != 0);
      maskn[i] = v;
    }
  }
}

// ---------------- 128x128 GEMM (m97 structure; m-inner XCD chunks) ----------
// MODE 0: qkv -> bf16 matrix [kM][2304] via 2-pass 64-row LDS transpose
// MODE 1: proj -> f32 out [kM][768] + bias
template<int MODE>
__global__ __launch_bounds__(256) void k_gemm128(const u16* __restrict__ A,
      const u16* __restrict__ wb, const float* __restrict__ bias,
      u16* __restrict__ outb, float* __restrict__ outf){
  __shared__ union SM {
    struct { u16 a[128*32]; u16 b[128*32]; } s;   // 16 KB staging
    u16 c2[64*136];                                // 17.4 KB epilogue half-tile
  } sm;
  constexpr int NB = (MODE==0) ? 18 : 6;
  const int wg = xcd_swz(blockIdx.x, gridDim.x);
  const int m0 = (wg / NB)*128;                    // m-inner within chunk
  const int N0 = (wg % NB)*128;
  const int sel = (MODE==0) ? (N0/768) : 3;
  const int jb  = (MODE==0) ? (N0%768) : N0;
  const u16* W = wb + (size_t)sel*589824;
  const int t = threadIdx.x;
  const int wave = t>>6, lane = t&63;
  const int g = lane>>4, cl = lane&15;
  const int wr2 = (wave>>1)*64, wc2 = (wave&1)*64;

  const int cid0 = wave*64 + lane;
  const int cid1 = cid0 + 256;
  const int ar0 = m0 + (cid0>>2) < kM ? m0 + (cid0>>2) : kM-1;
  const int ar1 = m0 + (cid1>>2) < kM ? m0 + (cid1>>2) : kM-1;
  const int ac0 = (cid0&3)<<3, ac1 = (cid1&3)<<3;
  const int br0 = jb + (cid0>>2), br1 = jb + (cid1>>2);
  u16* lA0 = &sm.s.a[(wave*64)*8];
  u16* lA1 = &sm.s.a[(256 + wave*64)*8];
  u16* lB0 = &sm.s.b[(wave*64)*8];
  u16* lB1 = &sm.s.b[(256 + wave*64)*8];

  f32x4 acc[4][4];
  #pragma unroll
  for (int i=0;i<4;i++)
    #pragma unroll
    for (int j=0;j<4;j++) acc[i][j] = (f32x4){0.f,0.f,0.f,0.f};

  for (int k0=0; k0<768; k0+=32){
    __syncthreads();
    GLL16(A + (size_t)ar0*768 + k0 + ac0, lA0);
    GLL16(A + (size_t)ar1*768 + k0 + ac1, lA1);
    GLL16(W + (size_t)br0*768 + k0 + ac0, lB0);
    GLL16(W + (size_t)br1*768 + k0 + ac1, lB1);
    __syncthreads();
    bf16x8 af[4], bfg[4];
    #pragma unroll
    for (int fm=0; fm<4; fm++)
      af[fm] = *reinterpret_cast<const bf16x8*>(&sm.s.a[(wr2+fm*16+cl)*32 + g*8]);
    #pragma unroll
    for (int fn=0; fn<4; fn++)
      bfg[fn] = *reinterpret_cast<const bf16x8*>(&sm.s.b[(wc2+fn*16+cl)*32 + g*8]);
    #pragma unroll
    for (int fm=0; fm<4; fm++)
      #pragma unroll
      for (int fn=0; fn<4; fn++)
        acc[fm][fn] = MFMA16(af[fm], bfg[fn], acc[fm][fn]);
  }

  if (MODE==0){
    // two 64-row passes through the 17.4KB transpose buffer
    #pragma unroll
    for (int ph=0; ph<2; ++ph){
      __syncthreads();
      if ((wave>>1) == ph){
        #pragma unroll
        for (int fm=0; fm<4; fm++)
          #pragma unroll
          for (int fn=0; fn<4; fn++)
            #pragma unroll
            for (int i=0;i<4;i++){
              int r = fm*16 + g*4 + i;           // row within this half
              int c = wc2 + fn*16 + cl;
              sm.c2[r*136 + c] = f2b(acc[fm][fn][i]);
            }
      }
      __syncthreads();
      #pragma unroll
      for (int it=0; it<4; it++){
        int cid = t + it*256;
        int r = cid >> 4, cc = (cid & 15) * 8;
        int gm = m0 + ph*64 + r;
        if (gm < kM){
          *reinterpret_cast<uint4*>(&outb[(size_t)gm*2304 + N0 + cc]) =
              *reinterpret_cast<const uint4*>(&sm.c2[r*136 + cc]);
        }
      }
    }
  } else {
    #pragma unroll
    for (int fm=0; fm<4; fm++)
      #pragma unroll
      for (int fn=0; fn<4; fn++)
        #pragma unroll
        for (int i=0;i<4;i++){
          int gm = m0 + wr2 + fm*16 + g*4 + i;
          if (gm >= kM) continue;
          int gc = jb + wc2 + fn*16 + cl;
          outf[(size_t)gm*768 + gc] = acc[fm][fn][i] + bias[gc];
        }
  }
}

// ---------------- depthwise pool + LN; block = (bh, 64-np slab, which) -------
__global__ __launch_bounds__(256) void k_pool3(const u16* __restrict__ qkvmat,
    const float* __restrict__ wq, const float* __restrict__ wk, const float* __restrict__ wv,
    const float* __restrict__ gq, const float* __restrict__ bq,
    const float* __restrict__ gk, const float* __restrict__ bk,
    const float* __restrict__ gv, const float* __restrict__ bv,
    u16* __restrict__ Qp, u16* __restrict__ Kp, u16* __restrict__ Vt){
  __shared__ u16 vt[64][72];                 // 9216 B, 16B-aligned rows
  const int which = blockIdx.y;
  const float* w9 = (which==0)?wq:(which==1)?wk:wv;
  const float* gg = (which==0)?gq:(which==1)?gk:gv;
  const float* bb2= (which==0)?bq:(which==1)?bk:bv;
  u16* out = (which==0)?Qp:(which==1)?Kp:Vt;

  const int wave = threadIdx.x>>6, d = threadIdx.x&63;
  const int wg  = xcd_swz(blockIdx.x, 96*17);   // 1632 % 8 == 0
  const int nb  = wg % 17;
  const int bh  = wg / 17;
  const int b = bh/12, h = bh - b*12;
  const int np0 = nb*64;
  const u16* base = qkvmat + ((size_t)b*1025)*2304 + which*768 + h*64;

  float wreg[9];
  #pragma unroll
  for (int j=0;j<9;j++) wreg[j] = w9[d*9+j];
  const float gd = gg[d], bd = bb2[d];

  for (int iter=0; iter<16; ++iter){
    const int np = np0 + iter*4 + wave;
    float v = 0.f;
    if (np < kN){
      if (np == 0){
        v = b2f(base[d]);
      } else {
        int y = (np-1)>>5, x = (np-1)&31;
        #pragma unroll
        for (int ky=0; ky<3; ky++){
          int yy = y+ky-1;
          if (yy<0 || yy>31) continue;
          #pragma unroll
          for (int kx=0; kx<3; kx++){
            int xx = x+kx-1;
            if (xx<0 || xx>31) continue;
            v += wreg[ky*3+kx] * b2f(base[(size_t)(1+yy*32+xx)*2304 + d]);
          }
        }
      }
      float s = v, s2 = v*v;
      #pragma unroll
      for (int off=1; off<64; off<<=1){ s += __shfl_xor(s, off); s2 += __shfl_xor(s2, off); }
      float mean = s*(1.f/64.f);
      float var  = s2*(1.f/64.f) - mean*mean;
      v = (v-mean)*rsqrtf(var+1e-5f)*gd + bd;
    }
    if (which==2) vt[d][iter*4+wave] = f2b(v);
    else if (np < kNP) out[((size_t)bh*kNP + np)*kD + d] = f2b(v);
  }

  if (which==2){
    __syncthreads();
    const int dr = threadIdx.x>>2, seg = threadIdx.x&3;
    if (np0 + seg*16 < kNP){
      u16* dst = Vt + ((size_t)bh*kD + dr)*kNP + np0 + seg*16;
      *reinterpret_cast<uint4*>(dst)     = *reinterpret_cast<const uint4*>(&vt[dr][seg*16]);
      *reinterpret_cast<uint4*>(dst + 8) = *reinterpret_cast<const uint4*>(&vt[dr][seg*16+8]);
    }
  }
}

// ---------------- attention: 512-thread, role-split phase 2 -----------------
// phase 1 (8 waves): swapped S^T=mfma(K,Q) -> e -> LDS, row sums.
// phase 2: waves 0-3 PV + ctx; waves 4-7 attn store (overlapped).
// |logit| <= 8 (LN'd q,k): no max pass. masked rows -> uniform 1/1025.
__global__ __launch_bounds__(512, 8) void k_attn(const u16* __restrict__ Qp, const u16* __restrict__ Kp,
    const u16* __restrict__ Vt, const int* __restrict__ maskn,
    float* __restrict__ attn_out, u16* __restrict__ ctx){
  constexpr int LDE = 1064;
  __shared__ u16 E[16*LDE];
  __shared__ float Lrow[16];
  __shared__ float Linv[16];
  const int wave = threadIdx.x>>6, lane = threadIdx.x&63;
  const int xcd  = blockIdx.x & 7;
  const int slot = blockIdx.x >> 3;          // 0..779
  const int bh = xcd*12 + slot/65;
  const int qt = slot%65;
  const int b  = bh / 12, h = bh - b*12;
  const int qbase = qt*16;
  const int g = lane>>4, cl = lane&15;

  if (threadIdx.x < 16) Lrow[threadIdx.x] = 0.f;
  __syncthreads();

  const u16* qrow = Qp + ((size_t)bh*kNP + (qbase + cl))*kD + g*8;
  bf16x8 aq0 = *reinterpret_cast<const bf16x8*>(qrow);
  bf16x8 aq1 = *reinterpret_cast<const bf16x8*>(qrow + 32);

  // per-lane row mask*scale (one scalar: lane owns q-row = cl)
  const int qi_l = qbase + cl;
  const float mqc = (qi_l < kN && maskn[b*kN + qi_l] != 0) ? kScale : 0.f;

  // ---- phase 1: S^T = mfma(K,Q) -> e -> packed b64 LDS writes, row sums ----
  const u16* kb = Kp + (size_t)bh*kNP*kD;
  float rsum = 0.f;
  u16* erow = &E[cl*LDE];
  #pragma unroll 1
  for (int kt=wave; kt<32; kt+=8){
    const int ktb = kt*32;
    const u16* kr = kb + (size_t)(ktb+cl)*kD + g*8;
    bf16x8 b00 = *reinterpret_cast<const bf16x8*>(kr);
    bf16x8 b01 = *reinterpret_cast<const bf16x8*>(kr+32);
    bf16x8 b10 = *reinterpret_cast<const bf16x8*>(kr+1024);
    bf16x8 b11 = *reinterpret_cast<const bf16x8*>(kr+1024+32);
    f32x4 s0 = {0.f,0.f,0.f,0.f}, s1 = {0.f,0.f,0.f,0.f};
    __builtin_amdgcn_s_setprio(1);
    s0 = MFMA16(b00,aq0,s0); s0 = MFMA16(b01,aq1,s0);   // swapped: S^T rows=k
    s1 = MFMA16(b10,aq0,s1); s1 = MFMA16(b11,aq1,s1);
    __builtin_amdgcn_s_setprio(0);
    float e0 = __expf(s0[0]*mqc), e1 = __expf(s0[1]*mqc);
    float e2 = __expf(s0[2]*mqc), e3 = __expf(s0[3]*mqc);
    float f0 = __expf(s1[0]*mqc), f1 = __expf(s1[1]*mqc);
    float f2 = __expf(s1[2]*mqc), f3 = __expf(s1[3]*mqc);
    rsum += ((e0+e1)+(e2+e3)) + ((f0+f1)+(f2+f3));
    uint2 w0v = { pkbf(e0,e1), pkbf(e2,e3) };
    uint2 w1v = { pkbf(f0,f1), pkbf(f2,f3) };
    *reinterpret_cast<uint2*>(&erow[ktb + 4*g])      = w0v;
    *reinterpret_cast<uint2*>(&erow[ktb + 16 + 4*g]) = w1v;
  }
  if (wave == 0){
    // kt = 32 boundary tile: only col 1024 (g==0, elem 0) is valid
    const int ktb = 1024;
    const u16* kr = kb + (size_t)(ktb+cl)*kD + g*8;
    bf16x8 b00 = *reinterpret_cast<const bf16x8*>(kr);
    bf16x8 b01 = *reinterpret_cast<const bf16x8*>(kr+32);
    f32x4 s0 = {0.f,0.f,0.f,0.f};
    s0 = MFMA16(b00,aq0,s0); s0 = MFMA16(b01,aq1,s0);
    float e0 = (g==0) ? __expf(s0[0]*mqc) : 0.f;
    rsum += e0;
    uint2 w0v = { pkbf(e0,0.f), 0u };
    uint2 zz  = { 0u, 0u };
    *reinterpret_cast<uint2*>(&erow[ktb + 4*g])      = w0v;
    *reinterpret_cast<uint2*>(&erow[ktb + 16 + 4*g]) = zz;
  }
  // reduce across the 4 g-lanes holding each row, one atomic per row per wave
  rsum += __shfl_xor(rsum, 16);
  rsum += __shfl_xor(rsum, 32);
  if (lane < 16) atomicAdd(&Lrow[cl], rsum);
  __syncthreads();
  if (threadIdx.x < 16) Linv[threadIdx.x] = 1.f/Lrow[threadIdx.x];
  __syncthreads();

  if (wave < 4){
    // ---- phase 2b: PV; wave owns 16 d-cols (TLP-hidden, 1-deep) ----
    const int d0 = wave*16;
    f32x4 oacc = (f32x4){0.f,0.f,0.f,0.f};
    const u16* vb = Vt + ((size_t)bh*kD + d0 + cl)*kNP;
    for (int kt=0; kt<33; kt++){
      const int ko = kt*32 + g*8;
      bf16x8 pa = *reinterpret_cast<const bf16x8*>(&E[cl*LDE + ko]);
      bf16x8 vv = *reinterpret_cast<const bf16x8*>(vb + ko);
      oacc = MFMA16(pa, vv, oacc);
    }
    #pragma unroll
    for (int i=0;i<4;i++){
      int row = g*4+i, qi = qbase+row;
      if (qi < kN){
        float val = oacc[i] * Linv[row];
        int dd = d0 + cl;
        if (qi >= 1) val += b2f(Qp[((size_t)bh*kNP + qi)*kD + dd]);
        ctx[((size_t)(b*kN + qi))*kC + h*kD + dd] = f2b(val);
      }
    }
  } else {
    // ---- phase 2a: attn tile as ONE contiguous span (waves 4-7) ----
    const int t2 = threadIdx.x - 256;
    size_t S = (size_t)bh*kN*kN + (size_t)qbase*kN;
    float* tp = attn_out + S;
    int rows = kN - qbase; if (rows > 16) rows = 16;
    int T = rows*kN;
    int head = (int)((4 - (S & 3)) & 3);
    int body4 = (T - head) >> 2;
    int tail = T - head - body4*4;
    if (t2 < head){
      int e = t2;
      unsigned row = ((unsigned)(e*16369))>>24;
      int col = e - (int)row*kN;
      tp[e] = b2f(E[row*LDE+col]) * Linv[row];
    }
    if (t2 < tail){
      int e = head + body4*4 + t2;
      unsigned row = ((unsigned)(e*16369))>>24;
      int col = e - (int)row*kN;
      tp[e] = b2f(E[row*LDE+col]) * Linv[row];
    }
    for (int idx = t2; idx < body4; idx += 256){
      int e = head + idx*4;
      unsigned row0 = ((unsigned)(e*16369))>>24;
      unsigned row3 = ((unsigned)((e+3)*16369))>>24;
      float4 vv;
      if (row0 == row3){
        int col = e - (int)row0*kN;
        const u16* ep = &E[row0*LDE + col];
        float li = Linv[row0];
        vv.x = b2f(ep[0])*li; vv.y = b2f(ep[1])*li;
        vv.z = b2f(ep[2])*li; vv.w = b2f(ep[3])*li;
      } else {
        float tmp[4];
        #pragma unroll
        for (int j=0;j<4;j++){
          int ee = e+j;
          unsigned row = ((unsigned)(ee*16369))>>24;
          int col = ee - (int)row*kN;
          tmp[j] = b2f(E[row*LDE+col]) * Linv[row];
        }
        vv.x=tmp[0]; vv.y=tmp[1]; vv.z=tmp[2]; vv.w=tmp[3];
      }
      *reinterpret_cast<float4*>(tp + e) = vv;
    }
  }
}

extern "C" void kernel_launch(void* const* d_in, const int* in_sizes, int n_in,
                              void* d_out, int out_size, void* d_ws, size_t ws_size,
                              hipStream_t stream) {
  const float* x    = (const float*)d_in[0];
  const void*  msk  = d_in[1];
  const float* Wq   = (const float*)d_in[2];
  const float* Wk   = (const float*)d_in[3];
  const float* Wv   = (const float*)d_in[4];
  const float* pw_q = (const float*)d_in[5];
  const float* pw_k = (const float*)d_in[6];
  const float* pw_v = (const float*)d_in[7];
  const float* gq   = (const float*)d_in[8];
  const float* bq   = (const float*)d_in[9];
  const float* gk   = (const float*)d_in[10];
  const float* bk   = (const float*)d_in[11];
  const float* gv   = (const float*)d_in[12];
  const float* bv   = (const float*)d_in[13];
  const float* Wp   = (const float*)d_in[14];
  const float* bp   = (const float*)d_in[15];

  char* ws = (char*)d_ws;
  u16* xb     = (u16*)(ws + 0);            // 12,595,200 B
  u16* wb     = (u16*)(ws + 12595200);     // 4,718,592 B (Wq,Wk,Wv,Wp)
  int* maskn  = (int*)(ws + 17313792);
  u16* qkvmat = (u16*)(ws + 17346816);     // [8200][2304] bf16 = 37,785,600 B
  u16* Qp     = (u16*)(ws + 55132416);
  u16* Kp     = (u16*)(ws + 68108544);
  u16* Vt     = (u16*)(ws + 81084672);
  u16* ctx    = (u16*)(ws + 17346816);     // aliases qkvmat (free after pooling)

  float* out1 = (float*)d_out;
  float* attn = out1 + (size_t)kM*kC;

  k_prep<<<8486, 256, 0, stream>>>(reinterpret_cast<const float4*>(x),
                                   Wq, Wk, Wv, Wp, (const unsigned char*)msk,
                                   xb, wb, maskn);
  k_gemm128<0><<<65*18, 256, 0, stream>>>(xb, wb, nullptr, qkvmat, nullptr);
  k_pool3<<<dim3(96*17,3), 256, 0, stream>>>(qkvmat, pw_q, pw_k, pw_v,
                                             gq, bq, gk, bk, gv, bv, Qp, Kp, Vt);
  // DIAGNOSTIC (R11): k_attn launched TWICE. k_attn is idempotent (its inputs
  // are disjoint from its outputs), so results are identical; the measured
  // total - 395.9us baseline = k_attn's standalone duration. Next round
  // removes the duplicate and targets whichever side the split indicts.
  k_attn<<<96*65, 512, 0, stream>>>(Qp, Kp, Vt, maskn, attn, ctx);
  k_attn<<<96*65, 512, 0, stream>>>(Qp, Kp, Vt, maskn, attn, ctx);
  k_gemm128<1><<<65*6, 256, 0, stream>>>(ctx, wb, bp, nullptr, out1);
}

// Round 12
// 525.509 us; speedup vs baseline: 1.1512x; 1.1512x over previous
//
#include <hip/hip_runtime.h>
#include <hip/hip_bf16.h>
#include <cstdint>
#include <cstddef>

typedef unsigned short u16;
typedef __attribute__((ext_vector_type(8))) short bf16x8;
typedef __attribute__((ext_vector_type(4))) float f32x4;

#define MFMA16(a,b,c) __builtin_amdgcn_mfma_f32_16x16x32_bf16(a,b,c,0,0,0)
#define GLL16(gp, lp) __builtin_amdgcn_global_load_lds( \
    (const __attribute__((address_space(1))) void*)(gp), \
    (__attribute__((address_space(3))) void*)(lp), 16, 0, 0)

static constexpr int kB = 8, kH = 12, kN = 1025, kC = 768, kD = 64;
static constexpr int kBH = kB*kH;          // 96
static constexpr int kNP = 1056;           // padded N (33*32)
static constexpr int kM  = kB*kN;          // 8200
static constexpr float kScale = 0.125f;

__device__ __forceinline__ u16 f2b(float f){
  unsigned u = __builtin_bit_cast(unsigned, f);
  u = (u + 0x7fffu + ((u>>16)&1u)) >> 16;
  return (u16)u;
}
__device__ __forceinline__ float b2f(u16 s){
  unsigned u = ((unsigned)s)<<16;
  return __builtin_bit_cast(float, u);
}
// pack two f32 -> one dword of 2 bf16 (lo=a, hi=b), HW RNE (T12 recipe)
__device__ __forceinline__ unsigned pkbf(float a, float b){
  unsigned r;
  asm("v_cvt_pk_bf16_f32 %0, %1, %2" : "=v"(r) : "v"(a), "v"(b));
  return r;
}
// bijective XCD-chunked swizzle (m204): contiguous work chunk per XCD
__device__ __forceinline__ int xcd_swz(int orig, int nwg){
  int q = nwg>>3, r = nwg&7;
  int xcd = orig&7, idx = orig>>3;
  return (xcd<r ? xcd*(q+1) : r*(q+1)+(xcd-r)*q) + idx;
}

// ---------------- fused prep: x->bf16, weights->bf16, mask normalize --------
// blocks [0,6150): conv_x ; [6150,8454): conv_w ; [8454,8486): mask
__global__ __launch_bounds__(256) void k_prep(const float4* __restrict__ x,
    const float* __restrict__ w0, const float* __restrict__ w1,
    const float* __restrict__ w2, const float* __restrict__ w3,
    const unsigned char* __restrict__ m,
    u16* __restrict__ xb, u16* __restrict__ wb, int* __restrict__ maskn){
  __shared__ int cnt;
  const int bid = blockIdx.x;
  if (bid < 6150){
    int i = bid*256 + threadIdx.x;          // exactly 1,574,400
    float4 v = x[i];
    ushort4 o; o.x=f2b(v.x); o.y=f2b(v.y); o.z=f2b(v.z); o.w=f2b(v.w);
    *reinterpret_cast<ushort4*>(xb + (size_t)i*4) = o;
  } else if (bid < 8454){
    int j = (bid-6150)*256 + threadIdx.x;   // exactly 589,824
    int sel = j/147456, i = j - sel*147456;
    const float* ws[4] = {w0,w1,w2,w3};
    float4 v = reinterpret_cast<const float4*>(ws[sel])[i];
    ushort4 o; o.x=f2b(v.x); o.y=f2b(v.y); o.z=f2b(v.z); o.w=f2b(v.w);
    *reinterpret_cast<ushort4*>(wb + (size_t)sel*589824 + (size_t)i*4) = o;
  } else {
    // mask dtype detect (bool8 vs int32/f32) on first 1024 bytes, then slice
    if (threadIdx.x==0) cnt = 0;
    __syncthreads();
    int local = 0;
    for (int i=threadIdx.x; i<1024; i+=256) local += (m[i]!=0);
    atomicAdd(&cnt, local);
    __syncthreads();
    bool b8 = (cnt > 512);
    int lb = bid - 8454;                    // 0..31
    for (int i = lb*256 + threadIdx.x; i < kM; i += 32*256){
      int v = b8 ? (m[i]!=0) : (reinterpret_cast<const int*>(m)[i] != 0);
      maskn[i] = v;
    }
  }
}

// ---------------- 128x128 GEMM (m97 structure; m-inner XCD chunks) ----------
// MODE 0: qkv -> bf16 matrix [kM][2304] via 2-pass 64-row LDS transpose
// MODE 1: proj -> f32 out [kM][768] + bias
template<int MODE>
__global__ __launch_bounds__(256) void k_gemm128(const u16* __restrict__ A,
      const u16* __restrict__ wb, const float* __restrict__ bias,
      u16* __restrict__ outb, float* __restrict__ outf){
  __shared__ union SM {
    struct { u16 a[128*32]; u16 b[128*32]; } s;   // 16 KB staging
    u16 c2[64*136];                                // 17.4 KB epilogue half-tile
  } sm;
  constexpr int NB = (MODE==0) ? 18 : 6;
  const int wg = xcd_swz(blockIdx.x, gridDim.x);
  const int m0 = (wg / NB)*128;                    // m-inner within chunk
  const int N0 = (wg % NB)*128;
  const int sel = (MODE==0) ? (N0/768) : 3;
  const int jb  = (MODE==0) ? (N0%768) : N0;
  const u16* W = wb + (size_t)sel*589824;
  const int t = threadIdx.x;
  const int wave = t>>6, lane = t&63;
  const int g = lane>>4, cl = lane&15;
  const int wr2 = (wave>>1)*64, wc2 = (wave&1)*64;

  const int cid0 = wave*64 + lane;
  const int cid1 = cid0 + 256;
  const int ar0 = m0 + (cid0>>2) < kM ? m0 + (cid0>>2) : kM-1;
  const int ar1 = m0 + (cid1>>2) < kM ? m0 + (cid1>>2) : kM-1;
  const int ac0 = (cid0&3)<<3, ac1 = (cid1&3)<<3;
  const int br0 = jb + (cid0>>2), br1 = jb + (cid1>>2);
  u16* lA0 = &sm.s.a[(wave*64)*8];
  u16* lA1 = &sm.s.a[(256 + wave*64)*8];
  u16* lB0 = &sm.s.b[(wave*64)*8];
  u16* lB1 = &sm.s.b[(256 + wave*64)*8];

  f32x4 acc[4][4];
  #pragma unroll
  for (int i=0;i<4;i++)
    #pragma unroll
    for (int j=0;j<4;j++) acc[i][j] = (f32x4){0.f,0.f,0.f,0.f};

  for (int k0=0; k0<768; k0+=32){
    __syncthreads();
    GLL16(A + (size_t)ar0*768 + k0 + ac0, lA0);
    GLL16(A + (size_t)ar1*768 + k0 + ac1, lA1);
    GLL16(W + (size_t)br0*768 + k0 + ac0, lB0);
    GLL16(W + (size_t)br1*768 + k0 + ac1, lB1);
    __syncthreads();
    bf16x8 af[4], bfg[4];
    #pragma unroll
    for (int fm=0; fm<4; fm++)
      af[fm] = *reinterpret_cast<const bf16x8*>(&sm.s.a[(wr2+fm*16+cl)*32 + g*8]);
    #pragma unroll
    for (int fn=0; fn<4; fn++)
      bfg[fn] = *reinterpret_cast<const bf16x8*>(&sm.s.b[(wc2+fn*16+cl)*32 + g*8]);
    #pragma unroll
    for (int fm=0; fm<4; fm++)
      #pragma unroll
      for (int fn=0; fn<4; fn++)
        acc[fm][fn] = MFMA16(af[fm], bfg[fn], acc[fm][fn]);
  }

  if (MODE==0){
    // two 64-row passes through the 17.4KB transpose buffer
    #pragma unroll
    for (int ph=0; ph<2; ++ph){
      __syncthreads();
      if ((wave>>1) == ph){
        #pragma unroll
        for (int fm=0; fm<4; fm++)
          #pragma unroll
          for (int fn=0; fn<4; fn++)
            #pragma unroll
            for (int i=0;i<4;i++){
              int r = fm*16 + g*4 + i;           // row within this half
              int c = wc2 + fn*16 + cl;
              sm.c2[r*136 + c] = f2b(acc[fm][fn][i]);
            }
      }
      __syncthreads();
      #pragma unroll
      for (int it=0; it<4; it++){
        int cid = t + it*256;
        int r = cid >> 4, cc = (cid & 15) * 8;
        int gm = m0 + ph*64 + r;
        if (gm < kM){
          *reinterpret_cast<uint4*>(&outb[(size_t)gm*2304 + N0 + cc]) =
              *reinterpret_cast<const uint4*>(&sm.c2[r*136 + cc]);
        }
      }
    }
  } else {
    #pragma unroll
    for (int fm=0; fm<4; fm++)
      #pragma unroll
      for (int fn=0; fn<4; fn++)
        #pragma unroll
        for (int i=0;i<4;i++){
          int gm = m0 + wr2 + fm*16 + g*4 + i;
          if (gm >= kM) continue;
          int gc = jb + wc2 + fn*16 + cl;
          outf[(size_t)gm*768 + gc] = acc[fm][fn][i] + bias[gc];
        }
  }
}

// ---------------- depthwise pool + LN; block = (bh, 64-np slab, which) -------
__global__ __launch_bounds__(256) void k_pool3(const u16* __restrict__ qkvmat,
    const float* __restrict__ wq, const float* __restrict__ wk, const float* __restrict__ wv,
    const float* __restrict__ gq, const float* __restrict__ bq,
    const float* __restrict__ gk, const float* __restrict__ bk,
    const float* __restrict__ gv, const float* __restrict__ bv,
    u16* __restrict__ Qp, u16* __restrict__ Kp, u16* __restrict__ Vt){
  __shared__ u16 vt[64][72];                 // 9216 B, 16B-aligned rows
  const int which = blockIdx.y;
  const float* w9 = (which==0)?wq:(which==1)?wk:wv;
  const float* gg = (which==0)?gq:(which==1)?gk:gv;
  const float* bb2= (which==0)?bq:(which==1)?bk:bv;
  u16* out = (which==0)?Qp:(which==1)?Kp:Vt;

  const int wave = threadIdx.x>>6, d = threadIdx.x&63;
  const int wg  = xcd_swz(blockIdx.x, 96*17);   // 1632 % 8 == 0
  const int nb  = wg % 17;
  const int bh  = wg / 17;
  const int b = bh/12, h = bh - b*12;
  const int np0 = nb*64;
  const u16* base = qkvmat + ((size_t)b*1025)*2304 + which*768 + h*64;

  float wreg[9];
  #pragma unroll
  for (int j=0;j<9;j++) wreg[j] = w9[d*9+j];
  const float gd = gg[d], bd = bb2[d];

  for (int iter=0; iter<16; ++iter){
    const int np = np0 + iter*4 + wave;
    float v = 0.f;
    if (np < kN){
      if (np == 0){
        v = b2f(base[d]);
      } else {
        int y = (np-1)>>5, x = (np-1)&31;
        #pragma unroll
        for (int ky=0; ky<3; ky++){
          int yy = y+ky-1;
          if (yy<0 || yy>31) continue;
          #pragma unroll
          for (int kx=0; kx<3; kx++){
            int xx = x+kx-1;
            if (xx<0 || xx>31) continue;
            v += wreg[ky*3+kx] * b2f(base[(size_t)(1+yy*32+xx)*2304 + d]);
          }
        }
      }
      float s = v, s2 = v*v;
      #pragma unroll
      for (int off=1; off<64; off<<=1){ s += __shfl_xor(s, off); s2 += __shfl_xor(s2, off); }
      float mean = s*(1.f/64.f);
      float var  = s2*(1.f/64.f) - mean*mean;
      v = (v-mean)*rsqrtf(var+1e-5f)*gd + bd;
    }
    if (which==2) vt[d][iter*4+wave] = f2b(v);
    else if (np < kNP) out[((size_t)bh*kNP + np)*kD + d] = f2b(v);
  }

  if (which==2){
    __syncthreads();
    const int dr = threadIdx.x>>2, seg = threadIdx.x&3;
    if (np0 + seg*16 < kNP){
      u16* dst = Vt + ((size_t)bh*kD + dr)*kNP + np0 + seg*16;
      *reinterpret_cast<uint4*>(dst)     = *reinterpret_cast<const uint4*>(&vt[dr][seg*16]);
      *reinterpret_cast<uint4*>(dst + 8) = *reinterpret_cast<const uint4*>(&vt[dr][seg*16+8]);
    }
  }
}

// ---------------- attention pass A: phase1 + PV + ctx + Linv ----------------
// NO attn-matrix store here (pass B streams it). 8 waves phase1; waves 0-3 PV.
__global__ __launch_bounds__(512, 8) void k_attn(const u16* __restrict__ Qp, const u16* __restrict__ Kp,
    const u16* __restrict__ Vt, const int* __restrict__ maskn,
    float* __restrict__ LinvG, u16* __restrict__ ctx){
  constexpr int LDE = 1064;
  __shared__ u16 E[16*LDE];
  __shared__ float Lrow[16];
  __shared__ float Linv[16];
  const int wave = threadIdx.x>>6, lane = threadIdx.x&63;
  const int xcd  = blockIdx.x & 7;
  const int slot = blockIdx.x >> 3;          // 0..779
  const int bh = xcd*12 + slot/65;
  const int qt = slot%65;
  const int b  = bh / 12, h = bh - b*12;
  const int qbase = qt*16;
  const int g = lane>>4, cl = lane&15;

  if (threadIdx.x < 16) Lrow[threadIdx.x] = 0.f;
  __syncthreads();

  const u16* qrow = Qp + ((size_t)bh*kNP + (qbase + cl))*kD + g*8;
  bf16x8 aq0 = *reinterpret_cast<const bf16x8*>(qrow);
  bf16x8 aq1 = *reinterpret_cast<const bf16x8*>(qrow + 32);

  const int qi_l = qbase + cl;
  const float mqc = (qi_l < kN && maskn[b*kN + qi_l] != 0) ? kScale : 0.f;

  // ---- phase 1: S^T = mfma(K,Q) -> e -> packed b64 LDS writes, row sums ----
  const u16* kb = Kp + (size_t)bh*kNP*kD;
  float rsum = 0.f;
  u16* erow = &E[cl*LDE];
  #pragma unroll 1
  for (int kt=wave; kt<32; kt+=8){
    const int ktb = kt*32;
    const u16* kr = kb + (size_t)(ktb+cl)*kD + g*8;
    bf16x8 b00 = *reinterpret_cast<const bf16x8*>(kr);
    bf16x8 b01 = *reinterpret_cast<const bf16x8*>(kr+32);
    bf16x8 b10 = *reinterpret_cast<const bf16x8*>(kr+1024);
    bf16x8 b11 = *reinterpret_cast<const bf16x8*>(kr+1024+32);
    f32x4 s0 = {0.f,0.f,0.f,0.f}, s1 = {0.f,0.f,0.f,0.f};
    __builtin_amdgcn_s_setprio(1);
    s0 = MFMA16(b00,aq0,s0); s0 = MFMA16(b01,aq1,s0);   // swapped: S^T rows=k
    s1 = MFMA16(b10,aq0,s1); s1 = MFMA16(b11,aq1,s1);
    __builtin_amdgcn_s_setprio(0);
    float e0 = __expf(s0[0]*mqc), e1 = __expf(s0[1]*mqc);
    float e2 = __expf(s0[2]*mqc), e3 = __expf(s0[3]*mqc);
    float f0 = __expf(s1[0]*mqc), f1 = __expf(s1[1]*mqc);
    float f2 = __expf(s1[2]*mqc), f3 = __expf(s1[3]*mqc);
    rsum += ((e0+e1)+(e2+e3)) + ((f0+f1)+(f2+f3));
    uint2 w0v = { pkbf(e0,e1), pkbf(e2,e3) };
    uint2 w1v = { pkbf(f0,f1), pkbf(f2,f3) };
    *reinterpret_cast<uint2*>(&erow[ktb + 4*g])      = w0v;
    *reinterpret_cast<uint2*>(&erow[ktb + 16 + 4*g]) = w1v;
  }
  if (wave == 0){
    // kt = 32 boundary tile: only col 1024 (g==0, elem 0) is valid
    const int ktb = 1024;
    const u16* kr = kb + (size_t)(ktb+cl)*kD + g*8;
    bf16x8 b00 = *reinterpret_cast<const bf16x8*>(kr);
    bf16x8 b01 = *reinterpret_cast<const bf16x8*>(kr+32);
    f32x4 s0 = {0.f,0.f,0.f,0.f};
    s0 = MFMA16(b00,aq0,s0); s0 = MFMA16(b01,aq1,s0);
    float e0 = (g==0) ? __expf(s0[0]*mqc) : 0.f;
    rsum += e0;
    uint2 w0v = { pkbf(e0,0.f), 0u };
    uint2 zz  = { 0u, 0u };
    *reinterpret_cast<uint2*>(&erow[ktb + 4*g])      = w0v;
    *reinterpret_cast<uint2*>(&erow[ktb + 16 + 4*g]) = zz;
  }
  rsum += __shfl_xor(rsum, 16);
  rsum += __shfl_xor(rsum, 32);
  if (lane < 16) atomicAdd(&Lrow[cl], rsum);
  __syncthreads();
  if (threadIdx.x < 16) Linv[threadIdx.x] = 1.f/Lrow[threadIdx.x];
  __syncthreads();

  if (wave < 4){
    // ---- PV; wave owns 16 d-cols ----
    const int d0 = wave*16;
    f32x4 oacc = (f32x4){0.f,0.f,0.f,0.f};
    const u16* vb = Vt + ((size_t)bh*kD + d0 + cl)*kNP;
    for (int kt=0; kt<33; kt++){
      const int ko = kt*32 + g*8;
      bf16x8 pa = *reinterpret_cast<const bf16x8*>(&E[cl*LDE + ko]);
      bf16x8 vv = *reinterpret_cast<const bf16x8*>(vb + ko);
      oacc = MFMA16(pa, vv, oacc);
    }
    #pragma unroll
    for (int i=0;i<4;i++){
      int row = g*4+i, qi = qbase+row;
      if (qi < kN){
        float val = oacc[i] * Linv[row];
        int dd = d0 + cl;
        if (qi >= 1) val += b2f(Qp[((size_t)bh*kNP + qi)*kD + dd]);
        ctx[((size_t)(b*kN + qi))*kC + h*kD + dd] = f2b(val);
      }
    }
  } else if (wave == 4){
    if (lane < 16) LinvG[(size_t)bh*kNP + qbase + lane] = Linv[lane];
  }
}

// ---------------- attention pass B: streaming attn store --------------------
// Recomputes S^T = mfma(K,Q) (cheap), p = exp(s*scale)*Linv, stores float4
// straight from registers: continuous store issue, no LDS, no barriers.
__global__ __launch_bounds__(256) void k_store(const u16* __restrict__ Qp,
    const u16* __restrict__ Kp, const int* __restrict__ maskn,
    const float* __restrict__ LinvG, float* __restrict__ attn_out){
  const int wave = threadIdx.x>>6, lane = threadIdx.x&63;
  const int xcd  = blockIdx.x & 7;
  const int slot = blockIdx.x >> 3;          // 0..779
  const int bh = xcd*12 + slot/65;
  const int qt = slot%65;
  const int b  = bh / 12;
  const int qbase = qt*16;
  const int g = lane>>4, cl = lane&15;

  const u16* qrow = Qp + ((size_t)bh*kNP + (qbase + cl))*kD + g*8;
  bf16x8 aq0 = *reinterpret_cast<const bf16x8*>(qrow);
  bf16x8 aq1 = *reinterpret_cast<const bf16x8*>(qrow + 32);

  const int qi_l = qbase + cl;
  const bool rowok = qi_l < kN;
  const float mqc = (rowok && maskn[b*kN + qi_l] != 0) ? kScale : 0.f;
  const float linv = LinvG[(size_t)bh*kNP + qi_l];

  const u16* kb = Kp + (size_t)bh*kNP*kD;
  float* arow = attn_out + (size_t)bh*kN*kN + (size_t)qi_l*kN;

  #pragma unroll 2
  for (int kt=wave; kt<32; kt+=4){
    const int ktb = kt*32;
    const u16* kr = kb + (size_t)(ktb+cl)*kD + g*8;
    bf16x8 b00 = *reinterpret_cast<const bf16x8*>(kr);
    bf16x8 b01 = *reinterpret_cast<const bf16x8*>(kr+32);
    bf16x8 b10 = *reinterpret_cast<const bf16x8*>(kr+1024);
    bf16x8 b11 = *reinterpret_cast<const bf16x8*>(kr+1024+32);
    f32x4 s0 = {0.f,0.f,0.f,0.f}, s1 = {0.f,0.f,0.f,0.f};
    s0 = MFMA16(b00,aq0,s0); s0 = MFMA16(b01,aq1,s0);
    s1 = MFMA16(b10,aq0,s1); s1 = MFMA16(b11,aq1,s1);
    f32x4 p0, p1;
    #pragma unroll
    for (int j=0;j<4;j++){
      p0[j] = __expf(s0[j]*mqc)*linv;
      p1[j] = __expf(s1[j]*mqc)*linv;
    }
    if (rowok){
      *reinterpret_cast<f32x4*>(arow + ktb + 4*g)      = p0;
      *reinterpret_cast<f32x4*>(arow + ktb + 16 + 4*g) = p1;
    }
  }
  if (wave == 0){
    // kt=32 boundary: only col 1024 valid
    const u16* kr = kb + (size_t)(1024+cl)*kD + g*8;
    bf16x8 b00 = *reinterpret_cast<const bf16x8*>(kr);
    bf16x8 b01 = *reinterpret_cast<const bf16x8*>(kr+32);
    f32x4 s0 = {0.f,0.f,0.f,0.f};
    s0 = MFMA16(b00,aq0,s0); s0 = MFMA16(b01,aq1,s0);
    if (rowok && g == 0) arow[1024] = __expf(s0[0]*mqc)*linv;
  }
}

extern "C" void kernel_launch(void* const* d_in, const int* in_sizes, int n_in,
                              void* d_out, int out_size, void* d_ws, size_t ws_size,
                              hipStream_t stream) {
  const float* x    = (const float*)d_in[0];
  const void*  msk  = d_in[1];
  const float* Wq   = (const float*)d_in[2];
  const float* Wk   = (const float*)d_in[3];
  const float* Wv   = (const float*)d_in[4];
  const float* pw_q = (const float*)d_in[5];
  const float* pw_k = (const float*)d_in[6];
  const float* pw_v = (const float*)d_in[7];
  const float* gq   = (const float*)d_in[8];
  const float* bq   = (const float*)d_in[9];
  const float* gk   = (const float*)d_in[10];
  const float* bk   = (const float*)d_in[11];
  const float* gv   = (const float*)d_in[12];
  const float* bv   = (const float*)d_in[13];
  const float* Wp   = (const float*)d_in[14];
  const float* bp   = (const float*)d_in[15];

  char* ws = (char*)d_ws;
  u16* xb     = (u16*)(ws + 0);            // 12,595,200 B
  u16* wb     = (u16*)(ws + 12595200);     // 4,718,592 B (Wq,Wk,Wv,Wp)
  int* maskn  = (int*)(ws + 17313792);
  u16* qkvmat = (u16*)(ws + 17346816);     // [8200][2304] bf16 = 37,785,600 B
  u16* ctx    = (u16*)(ws + 17346816);     // aliases qkvmat (dead after pooling)
  float* LinvG= (float*)(ws + 29942016);   // 405,504 B, behind ctx in old qkvmat
  u16* Qp     = (u16*)(ws + 55132416);
  u16* Kp     = (u16*)(ws + 68108544);
  u16* Vt     = (u16*)(ws + 81084672);

  float* out1 = (float*)d_out;
  float* attn = out1 + (size_t)kM*kC;

  k_prep<<<8486, 256, 0, stream>>>(reinterpret_cast<const float4*>(x),
                                   Wq, Wk, Wv, Wp, (const unsigned char*)msk,
                                   xb, wb, maskn);
  k_gemm128<0><<<65*18, 256, 0, stream>>>(xb, wb, nullptr, qkvmat, nullptr);
  k_pool3<<<dim3(96*17,3), 256, 0, stream>>>(qkvmat, pw_q, pw_k, pw_v,
                                             gq, bq, gk, bk, gv, bv, Qp, Kp, Vt);
  k_attn<<<96*65, 512, 0, stream>>>(Qp, Kp, Vt, maskn, LinvG, ctx);
  k_store<<<96*65, 256, 0, stream>>>(Qp, Kp, maskn, LinvG, attn);
  k_gemm128<1><<<65*6, 256, 0, stream>>>(ctx, wb, bp, nullptr, out1);
}

// Round 13
// 389.188 us; speedup vs baseline: 1.5544x; 1.3503x over previous
//
#include <hip/hip_runtime.h>
#include <hip/hip_bf16.h>
#include <cstdint>
#include <cstddef>

typedef unsigned short u16;
typedef __attribute__((ext_vector_type(8))) short bf16x8;
typedef __attribute__((ext_vector_type(4))) float f32x4;

#define MFMA16(a,b,c) __builtin_amdgcn_mfma_f32_16x16x32_bf16(a,b,c,0,0,0)
#define GLL16(gp, lp) __builtin_amdgcn_global_load_lds( \
    (const __attribute__((address_space(1))) void*)(gp), \
    (__attribute__((address_space(3))) void*)(lp), 16, 0, 0)

static constexpr int kB = 8, kH = 12, kN = 1025, kC = 768, kD = 64;
static constexpr int kBH = kB*kH;          // 96
static constexpr int kNP = 1056;           // padded N (33*32)
static constexpr int kM  = kB*kN;          // 8200
static constexpr float kScale = 0.125f;

__device__ __forceinline__ u16 f2b(float f){
  unsigned u = __builtin_bit_cast(unsigned, f);
  u = (u + 0x7fffu + ((u>>16)&1u)) >> 16;
  return (u16)u;
}
__device__ __forceinline__ float b2f(u16 s){
  unsigned u = ((unsigned)s)<<16;
  return __builtin_bit_cast(float, u);
}
// pack two f32 -> one dword of 2 bf16 (lo=a, hi=b), HW RNE (T12 recipe)
__device__ __forceinline__ unsigned pkbf(float a, float b){
  unsigned r;
  asm("v_cvt_pk_bf16_f32 %0, %1, %2" : "=v"(r) : "v"(a), "v"(b));
  return r;
}
// exact magic division by 1025 for e < 32800 (err bound 961*32800 < 2^26)
__device__ __forceinline__ unsigned div1025(unsigned e){
  return (unsigned)(((unsigned long long)e * 65473ull) >> 26);
}
// bijective XCD-chunked swizzle (m204): contiguous work chunk per XCD
__device__ __forceinline__ int xcd_swz(int orig, int nwg){
  int q = nwg>>3, r = nwg&7;
  int xcd = orig&7, idx = orig>>3;
  return (xcd<r ? xcd*(q+1) : r*(q+1)+(xcd-r)*q) + idx;
}

// ---------------- fused prep: x->bf16, weights->bf16, mask normalize --------
__global__ __launch_bounds__(256) void k_prep(const float4* __restrict__ x,
    const float* __restrict__ w0, const float* __restrict__ w1,
    const float* __restrict__ w2, const float* __restrict__ w3,
    const unsigned char* __restrict__ m,
    u16* __restrict__ xb, u16* __restrict__ wb, int* __restrict__ maskn){
  __shared__ int cnt;
  const int bid = blockIdx.x;
  if (bid < 6150){
    int i = bid*256 + threadIdx.x;          // exactly 1,574,400
    float4 v = x[i];
    ushort4 o; o.x=f2b(v.x); o.y=f2b(v.y); o.z=f2b(v.z); o.w=f2b(v.w);
    *reinterpret_cast<ushort4*>(xb + (size_t)i*4) = o;
  } else if (bid < 8454){
    int j = (bid-6150)*256 + threadIdx.x;   // exactly 589,824
    int sel = j/147456, i = j - sel*147456;
    const float* ws[4] = {w0,w1,w2,w3};
    float4 v = reinterpret_cast<const float4*>(ws[sel])[i];
    ushort4 o; o.x=f2b(v.x); o.y=f2b(v.y); o.z=f2b(v.z); o.w=f2b(v.w);
    *reinterpret_cast<ushort4*>(wb + (size_t)sel*589824 + (size_t)i*4) = o;
  } else {
    if (threadIdx.x==0) cnt = 0;
    __syncthreads();
    int local = 0;
    for (int i=threadIdx.x; i<1024; i+=256) local += (m[i]!=0);
    atomicAdd(&cnt, local);
    __syncthreads();
    bool b8 = (cnt > 512);
    int lb = bid - 8454;                    // 0..31
    for (int i = lb*256 + threadIdx.x; i < kM; i += 32*256){
      int v = b8 ? (m[i]!=0) : (reinterpret_cast<const int*>(m)[i] != 0);
      maskn[i] = v;
    }
  }
}

// ---------------- 128x128 GEMM (m97 structure; m-inner XCD chunks) ----------
template<int MODE>
__global__ __launch_bounds__(256) void k_gemm128(const u16* __restrict__ A,
      const u16* __restrict__ wb, const float* __restrict__ bias,
      u16* __restrict__ outb, float* __restrict__ outf){
  __shared__ union SM {
    struct { u16 a[128*32]; u16 b[128*32]; } s;   // 16 KB staging
    u16 c2[64*136];                                // 17.4 KB epilogue half-tile
  } sm;
  constexpr int NB = (MODE==0) ? 18 : 6;
  const int wg = xcd_swz(blockIdx.x, gridDim.x);
  const int m0 = (wg / NB)*128;                    // m-inner within chunk
  const int N0 = (wg % NB)*128;
  const int sel = (MODE==0) ? (N0/768) : 3;
  const int jb  = (MODE==0) ? (N0%768) : N0;
  const u16* W = wb + (size_t)sel*589824;
  const int t = threadIdx.x;
  const int wave = t>>6, lane = t&63;
  const int g = lane>>4, cl = lane&15;
  const int wr2 = (wave>>1)*64, wc2 = (wave&1)*64;

  const int cid0 = wave*64 + lane;
  const int cid1 = cid0 + 256;
  const int ar0 = m0 + (cid0>>2) < kM ? m0 + (cid0>>2) : kM-1;
  const int ar1 = m0 + (cid1>>2) < kM ? m0 + (cid1>>2) : kM-1;
  const int ac0 = (cid0&3)<<3, ac1 = (cid1&3)<<3;
  const int br0 = jb + (cid0>>2), br1 = jb + (cid1>>2);
  u16* lA0 = &sm.s.a[(wave*64)*8];
  u16* lA1 = &sm.s.a[(256 + wave*64)*8];
  u16* lB0 = &sm.s.b[(wave*64)*8];
  u16* lB1 = &sm.s.b[(256 + wave*64)*8];

  f32x4 acc[4][4];
  #pragma unroll
  for (int i=0;i<4;i++)
    #pragma unroll
    for (int j=0;j<4;j++) acc[i][j] = (f32x4){0.f,0.f,0.f,0.f};

  for (int k0=0; k0<768; k0+=32){
    __syncthreads();
    GLL16(A + (size_t)ar0*768 + k0 + ac0, lA0);
    GLL16(A + (size_t)ar1*768 + k0 + ac1, lA1);
    GLL16(W + (size_t)br0*768 + k0 + ac0, lB0);
    GLL16(W + (size_t)br1*768 + k0 + ac1, lB1);
    __syncthreads();
    bf16x8 af[4], bfg[4];
    #pragma unroll
    for (int fm=0; fm<4; fm++)
      af[fm] = *reinterpret_cast<const bf16x8*>(&sm.s.a[(wr2+fm*16+cl)*32 + g*8]);
    #pragma unroll
    for (int fn=0; fn<4; fn++)
      bfg[fn] = *reinterpret_cast<const bf16x8*>(&sm.s.b[(wc2+fn*16+cl)*32 + g*8]);
    #pragma unroll
    for (int fm=0; fm<4; fm++)
      #pragma unroll
      for (int fn=0; fn<4; fn++)
        acc[fm][fn] = MFMA16(af[fm], bfg[fn], acc[fm][fn]);
  }

  if (MODE==0){
    #pragma unroll
    for (int ph=0; ph<2; ++ph){
      __syncthreads();
      if ((wave>>1) == ph){
        #pragma unroll
        for (int fm=0; fm<4; fm++)
          #pragma unroll
          for (int fn=0; fn<4; fn++)
            #pragma unroll
            for (int i=0;i<4;i++){
              int r = fm*16 + g*4 + i;
              int c = wc2 + fn*16 + cl;
              sm.c2[r*136 + c] = f2b(acc[fm][fn][i]);
            }
      }
      __syncthreads();
      #pragma unroll
      for (int it=0; it<4; it++){
        int cid = t + it*256;
        int r = cid >> 4, cc = (cid & 15) * 8;
        int gm = m0 + ph*64 + r;
        if (gm < kM){
          *reinterpret_cast<uint4*>(&outb[(size_t)gm*2304 + N0 + cc]) =
              *reinterpret_cast<const uint4*>(&sm.c2[r*136 + cc]);
        }
      }
    }
  } else {
    #pragma unroll
    for (int fm=0; fm<4; fm++)
      #pragma unroll
      for (int fn=0; fn<4; fn++)
        #pragma unroll
        for (int i=0;i<4;i++){
          int gm = m0 + wr2 + fm*16 + g*4 + i;
          if (gm >= kM) continue;
          int gc = jb + wc2 + fn*16 + cl;
          outf[(size_t)gm*768 + gc] = acc[fm][fn][i] + bias[gc];
        }
  }
}

// ---------------- depthwise pool + LN; block = (bh, 64-np slab, which) -------
__global__ __launch_bounds__(256) void k_pool3(const u16* __restrict__ qkvmat,
    const float* __restrict__ wq, const float* __restrict__ wk, const float* __restrict__ wv,
    const float* __restrict__ gq, const float* __restrict__ bq,
    const float* __restrict__ gk, const float* __restrict__ bk,
    const float* __restrict__ gv, const float* __restrict__ bv,
    u16* __restrict__ Qp, u16* __restrict__ Kp, u16* __restrict__ Vt){
  __shared__ u16 vt[64][72];
  const int which = blockIdx.y;
  const float* w9 = (which==0)?wq:(which==1)?wk:wv;
  const float* gg = (which==0)?gq:(which==1)?gk:gv;
  const float* bb2= (which==0)?bq:(which==1)?bk:bv;
  u16* out = (which==0)?Qp:(which==1)?Kp:Vt;

  const int wave = threadIdx.x>>6, d = threadIdx.x&63;
  const int wg  = xcd_swz(blockIdx.x, 96*17);
  const int nb  = wg % 17;
  const int bh  = wg / 17;
  const int b = bh/12, h = bh - b*12;
  const int np0 = nb*64;
  const u16* base = qkvmat + ((size_t)b*1025)*2304 + which*768 + h*64;

  float wreg[9];
  #pragma unroll
  for (int j=0;j<9;j++) wreg[j] = w9[d*9+j];
  const float gd = gg[d], bd = bb2[d];

  for (int iter=0; iter<16; ++iter){
    const int np = np0 + iter*4 + wave;
    float v = 0.f;
    if (np < kN){
      if (np == 0){
        v = b2f(base[d]);
      } else {
        int y = (np-1)>>5, x = (np-1)&31;
        #pragma unroll
        for (int ky=0; ky<3; ky++){
          int yy = y+ky-1;
          if (yy<0 || yy>31) continue;
          #pragma unroll
          for (int kx=0; kx<3; kx++){
            int xx = x+kx-1;
            if (xx<0 || xx>31) continue;
            v += wreg[ky*3+kx] * b2f(base[(size_t)(1+yy*32+xx)*2304 + d]);
          }
        }
      }
      float s = v, s2 = v*v;
      #pragma unroll
      for (int off=1; off<64; off<<=1){ s += __shfl_xor(s, off); s2 += __shfl_xor(s2, off); }
      float mean = s*(1.f/64.f);
      float var  = s2*(1.f/64.f) - mean*mean;
      v = (v-mean)*rsqrtf(var+1e-5f)*gd + bd;
    }
    if (which==2) vt[d][iter*4+wave] = f2b(v);
    else if (np < kNP) out[((size_t)bh*kNP + np)*kD + d] = f2b(v);
  }

  if (which==2){
    __syncthreads();
    const int dr = threadIdx.x>>2, seg = threadIdx.x&3;
    if (np0 + seg*16 < kNP){
      u16* dst = Vt + ((size_t)bh*kD + dr)*kNP + np0 + seg*16;
      *reinterpret_cast<uint4*>(dst)     = *reinterpret_cast<const uint4*>(&vt[dr][seg*16]);
      *reinterpret_cast<uint4*>(dst + 8) = *reinterpret_cast<const uint4*>(&vt[dr][seg*16+8]);
    }
  }
}

// ---------------- attention: QBLK=32, 512 thr, fused store ------------------
// phase 1 (8 waves): each K-tile feeds BOTH 16-row groups (8 MFMA / tile).
// phase 2: waves 0-3 PV (V shared across groups) then join store;
//          waves 4-7 store the first 5/8 of the 131KB span immediately.
__global__ __launch_bounds__(512, 4) void k_attn(const u16* __restrict__ Qp, const u16* __restrict__ Kp,
    const u16* __restrict__ Vt, const int* __restrict__ maskn,
    float* __restrict__ attn_out, u16* __restrict__ ctx){
  constexpr int LDE = 1064;
  __shared__ u16 E[32*LDE];                  // 68,096 B
  __shared__ float Lrow[32];
  __shared__ float Linv[32];
  const int wave = threadIdx.x>>6, lane = threadIdx.x&63;
  const int xcd  = blockIdx.x & 7;
  const int slot = blockIdx.x >> 3;          // 0..395
  const int bh = xcd*12 + slot/33;
  const int qt = slot%33;
  const int b  = bh / 12, h = bh - b*12;
  const int qbase = qt*32;
  const int g = lane>>4, cl = lane&15;

  if (threadIdx.x < 32) Lrow[threadIdx.x] = 0.f;
  __syncthreads();

  const u16* qrow0 = Qp + ((size_t)bh*kNP + (qbase + cl))*kD + g*8;
  bf16x8 aq0 = *reinterpret_cast<const bf16x8*>(qrow0);
  bf16x8 aq1 = *reinterpret_cast<const bf16x8*>(qrow0 + 32);
  bf16x8 aq2 = *reinterpret_cast<const bf16x8*>(qrow0 + 16*kD);
  bf16x8 aq3 = *reinterpret_cast<const bf16x8*>(qrow0 + 16*kD + 32);

  const int qi0 = qbase + cl, qi1 = qbase + 16 + cl;
  const float mq0 = (qi0 < kN && maskn[b*kN + qi0] != 0) ? kScale : 0.f;
  const float mq1 = (qi1 < kN && maskn[b*kN + qi1] != 0) ? kScale : 0.f;

  // ---- phase 1 ----
  const u16* kb = Kp + (size_t)bh*kNP*kD;
  float rs0 = 0.f, rs1 = 0.f;
  u16* erow0 = &E[cl*LDE];
  u16* erow1 = &E[(16+cl)*LDE];
  #pragma unroll 1
  for (int kt=wave; kt<32; kt+=8){
    const int ktb = kt*32;
    const u16* kr = kb + (size_t)(ktb+cl)*kD + g*8;
    bf16x8 b00 = *reinterpret_cast<const bf16x8*>(kr);
    bf16x8 b01 = *reinterpret_cast<const bf16x8*>(kr+32);
    bf16x8 b10 = *reinterpret_cast<const bf16x8*>(kr+1024);
    bf16x8 b11 = *reinterpret_cast<const bf16x8*>(kr+1024+32);
    f32x4 s0 = {0.f,0.f,0.f,0.f}, s1 = {0.f,0.f,0.f,0.f};
    f32x4 s2 = {0.f,0.f,0.f,0.f}, s3 = {0.f,0.f,0.f,0.f};
    __builtin_amdgcn_s_setprio(1);
    s0 = MFMA16(b00,aq0,s0); s0 = MFMA16(b01,aq1,s0);
    s1 = MFMA16(b10,aq0,s1); s1 = MFMA16(b11,aq1,s1);
    s2 = MFMA16(b00,aq2,s2); s2 = MFMA16(b01,aq3,s2);
    s3 = MFMA16(b10,aq2,s3); s3 = MFMA16(b11,aq3,s3);
    __builtin_amdgcn_s_setprio(0);
    float e0=__expf(s0[0]*mq0), e1=__expf(s0[1]*mq0), e2=__expf(s0[2]*mq0), e3=__expf(s0[3]*mq0);
    float f0=__expf(s1[0]*mq0), f1=__expf(s1[1]*mq0), f2=__expf(s1[2]*mq0), f3=__expf(s1[3]*mq0);
    float g0=__expf(s2[0]*mq1), g1=__expf(s2[1]*mq1), g2=__expf(s2[2]*mq1), g3=__expf(s2[3]*mq1);
    float h0=__expf(s3[0]*mq1), h1=__expf(s3[1]*mq1), h2=__expf(s3[2]*mq1), h3=__expf(s3[3]*mq1);
    rs0 += ((e0+e1)+(e2+e3)) + ((f0+f1)+(f2+f3));
    rs1 += ((g0+g1)+(g2+g3)) + ((h0+h1)+(h2+h3));
    uint2 w0v = { pkbf(e0,e1), pkbf(e2,e3) };
    uint2 w1v = { pkbf(f0,f1), pkbf(f2,f3) };
    uint2 w2v = { pkbf(g0,g1), pkbf(g2,g3) };
    uint2 w3v = { pkbf(h0,h1), pkbf(h2,h3) };
    *reinterpret_cast<uint2*>(&erow0[ktb + 4*g])      = w0v;
    *reinterpret_cast<uint2*>(&erow0[ktb + 16 + 4*g]) = w1v;
    *reinterpret_cast<uint2*>(&erow1[ktb + 4*g])      = w2v;
    *reinterpret_cast<uint2*>(&erow1[ktb + 16 + 4*g]) = w3v;
  }
  if (wave == 0){
    // kt = 32 boundary tile: only col 1024 (g==0, reg 0) is valid
    const int ktb = 1024;
    const u16* kr = kb + (size_t)(ktb+cl)*kD + g*8;
    bf16x8 b00 = *reinterpret_cast<const bf16x8*>(kr);
    bf16x8 b01 = *reinterpret_cast<const bf16x8*>(kr+32);
    f32x4 s0 = {0.f,0.f,0.f,0.f}, s2 = {0.f,0.f,0.f,0.f};
    s0 = MFMA16(b00,aq0,s0); s0 = MFMA16(b01,aq1,s0);
    s2 = MFMA16(b00,aq2,s2); s2 = MFMA16(b01,aq3,s2);
    float e0 = (g==0) ? __expf(s0[0]*mq0) : 0.f;
    float g0 = (g==0) ? __expf(s2[0]*mq1) : 0.f;
    rs0 += e0; rs1 += g0;
    uint2 w0v = { pkbf(e0,0.f), 0u };
    uint2 w2v = { pkbf(g0,0.f), 0u };
    uint2 zz  = { 0u, 0u };
    *reinterpret_cast<uint2*>(&erow0[ktb + 4*g])      = w0v;
    *reinterpret_cast<uint2*>(&erow0[ktb + 16 + 4*g]) = zz;
    *reinterpret_cast<uint2*>(&erow1[ktb + 4*g])      = w2v;
    *reinterpret_cast<uint2*>(&erow1[ktb + 16 + 4*g]) = zz;
  }
  rs0 += __shfl_xor(rs0, 16);  rs0 += __shfl_xor(rs0, 32);
  rs1 += __shfl_xor(rs1, 16);  rs1 += __shfl_xor(rs1, 32);
  if (lane < 16){
    atomicAdd(&Lrow[cl], rs0);
    atomicAdd(&Lrow[16+cl], rs1);
  }
  __syncthreads();
  if (threadIdx.x < 32) Linv[threadIdx.x] = 1.f/Lrow[threadIdx.x];
  __syncthreads();

  // ---- phase 2: store span bookkeeping (shared by both wave roles) ----
  size_t S = (size_t)bh*kN*kN + (size_t)qbase*kN;
  float* tp = attn_out + S;
  int rows = kN - qbase; if (rows > 32) rows = 32;
  int T = rows*kN;
  int head = (int)((4 - (S & 3)) & 3);
  int body4 = (T - head) >> 2;
  int tail = T - head - body4*4;
  int B1 = (body4*5) >> 3;                  // waves 4-7 take [0,B1)

  if (wave >= 4){
    const int t2 = threadIdx.x - 256;
    if (t2 < head){
      int e = t2;
      unsigned row = div1025((unsigned)e);
      int col = e - (int)row*kN;
      tp[e] = b2f(E[row*LDE+col]) * Linv[row];
    }
    if (t2 < tail){
      int e = head + body4*4 + t2;
      unsigned row = div1025((unsigned)e);
      int col = e - (int)row*kN;
      tp[e] = b2f(E[row*LDE+col]) * Linv[row];
    }
    for (int idx = t2; idx < B1; idx += 256){
      int e = head + idx*4;
      unsigned row0 = div1025((unsigned)e);
      unsigned row3 = div1025((unsigned)(e+3));
      float4 vv;
      if (row0 == row3){
        int col = e - (int)row0*kN;
        const u16* ep = &E[row0*LDE + col];
        float li = Linv[row0];
        vv.x = b2f(ep[0])*li; vv.y = b2f(ep[1])*li;
        vv.z = b2f(ep[2])*li; vv.w = b2f(ep[3])*li;
      } else {
        float tmp[4];
        #pragma unroll
        for (int j=0;j<4;j++){
          int ee = e+j;
          unsigned row = div1025((unsigned)ee);
          int col = ee - (int)row*kN;
          tmp[j] = b2f(E[row*LDE+col]) * Linv[row];
        }
        vv.x=tmp[0]; vv.y=tmp[1]; vv.z=tmp[2]; vv.w=tmp[3];
      }
      *reinterpret_cast<float4*>(tp + e) = vv;
    }
  } else {
    // ---- PV for both row groups; wave owns 16 d-cols ----
    const int d0 = wave*16;
    f32x4 oa0 = (f32x4){0.f,0.f,0.f,0.f};
    f32x4 oa1 = (f32x4){0.f,0.f,0.f,0.f};
    const u16* vb = Vt + ((size_t)bh*kD + d0 + cl)*kNP;
    for (int kt=0; kt<33; kt++){
      const int ko = kt*32 + g*8;
      bf16x8 vv = *reinterpret_cast<const bf16x8*>(vb + ko);
      bf16x8 pa0 = *reinterpret_cast<const bf16x8*>(&E[cl*LDE + ko]);
      bf16x8 pa1 = *reinterpret_cast<const bf16x8*>(&E[(16+cl)*LDE + ko]);
      oa0 = MFMA16(pa0, vv, oa0);
      oa1 = MFMA16(pa1, vv, oa1);
    }
    #pragma unroll
    for (int i=0;i<4;i++){
      int row = g*4+i, qi = qbase+row;
      int dd = d0 + cl;
      if (qi < kN){
        float val = oa0[i] * Linv[row];
        if (qi >= 1) val += b2f(Qp[((size_t)bh*kNP + qi)*kD + dd]);
        ctx[((size_t)(b*kN + qi))*kC + h*kD + dd] = f2b(val);
      }
      int row1 = 16 + g*4 + i, qi1b = qbase + row1;
      if (qi1b < kN){
        float val = oa1[i] * Linv[row1];
        if (qi1b >= 1) val += b2f(Qp[((size_t)bh*kNP + qi1b)*kD + dd]);
        ctx[((size_t)(b*kN + qi1b))*kC + h*kD + dd] = f2b(val);
      }
    }
    // join the store: waves 0-3 cover [B1, body4)
    for (int idx = B1 + threadIdx.x; idx < body4; idx += 256){
      int e = head + idx*4;
      unsigned row0 = div1025((unsigned)e);
      unsigned row3 = div1025((unsigned)(e+3));
      float4 vv;
      if (row0 == row3){
        int col = e - (int)row0*kN;
        const u16* ep = &E[row0*LDE + col];
        float li = Linv[row0];
        vv.x = b2f(ep[0])*li; vv.y = b2f(ep[1])*li;
        vv.z = b2f(ep[2])*li; vv.w = b2f(ep[3])*li;
      } else {
        float tmp[4];
        #pragma unroll
        for (int j=0;j<4;j++){
          int ee = e+j;
          unsigned row = div1025((unsigned)ee);
          int col = ee - (int)row*kN;
          tmp[j] = b2f(E[row*LDE+col]) * Linv[row];
        }
        vv.x=tmp[0]; vv.y=tmp[1]; vv.z=tmp[2]; vv.w=tmp[3];
      }
      *reinterpret_cast<float4*>(tp + e) = vv;
    }
  }
}

extern "C" void kernel_launch(void* const* d_in, const int* in_sizes, int n_in,
                              void* d_out, int out_size, void* d_ws, size_t ws_size,
                              hipStream_t stream) {
  const float* x    = (const float*)d_in[0];
  const void*  msk  = d_in[1];
  const float* Wq   = (const float*)d_in[2];
  const float* Wk   = (const float*)d_in[3];
  const float* Wv   = (const float*)d_in[4];
  const float* pw_q = (const float*)d_in[5];
  const float* pw_k = (const float*)d_in[6];
  const float* pw_v = (const float*)d_in[7];
  const float* gq   = (const float*)d_in[8];
  const float* bq   = (const float*)d_in[9];
  const float* gk   = (const float*)d_in[10];
  const float* bk   = (const float*)d_in[11];
  const float* gv   = (const float*)d_in[12];
  const float* bv   = (const float*)d_in[13];
  const float* Wp   = (const float*)d_in[14];
  const float* bp   = (const float*)d_in[15];

  char* ws = (char*)d_ws;
  u16* xb     = (u16*)(ws + 0);            // 12,595,200 B
  u16* wb     = (u16*)(ws + 12595200);     // 4,718,592 B (Wq,Wk,Wv,Wp)
  int* maskn  = (int*)(ws + 17313792);
  u16* qkvmat = (u16*)(ws + 17346816);     // [8200][2304] bf16 = 37,785,600 B
  u16* Qp     = (u16*)(ws + 55132416);
  u16* Kp     = (u16*)(ws + 68108544);
  u16* Vt     = (u16*)(ws + 81084672);
  u16* ctx    = (u16*)(ws + 17346816);     // aliases qkvmat (dead after pooling)

  float* out1 = (float*)d_out;
  float* attn = out1 + (size_t)kM*kC;

  k_prep<<<8486, 256, 0, stream>>>(reinterpret_cast<const float4*>(x),
                                   Wq, Wk, Wv, Wp, (const unsigned char*)msk,
                                   xb, wb, maskn);
  k_gemm128<0><<<65*18, 256, 0, stream>>>(xb, wb, nullptr, qkvmat, nullptr);
  k_pool3<<<dim3(96*17,3), 256, 0, stream>>>(qkvmat, pw_q, pw_k, pw_v,
                                             gq, bq, gk, bk, gv, bv, Qp, Kp, Vt);
  k_attn<<<96*33, 512, 0, stream>>>(Qp, Kp, Vt, maskn, attn, ctx);
  k_gemm128<1><<<65*6, 256, 0, stream>>>(ctx, wb, bp, nullptr, out1);
}